// Round 1
// baseline (727.008 us; speedup 1.0000x reference)
//
#include <hip/hip_runtime.h>
#include <hip/hip_bf16.h>
#include <cstdint>
#include <cstddef>

using bf16 = __hip_bfloat16;

typedef short s16x8 __attribute__((ext_vector_type(8)));
typedef short s16x4 __attribute__((ext_vector_type(4)));
typedef float f32x4 __attribute__((ext_vector_type(4)));

#define TM 128
#define TN 128
#define BK2 32          // K per pipeline step
#define NT 32           // K / BK2
#define CH 32           // scan chunks
#define CS 64           // steps per chunk (CH*CS = 2048)

// ---- static device scratch (sidesteps unknown ws_size) -------------------
__device__ __align__(16) bf16  g_xb[16384 * 1024];      // 32 MiB: x in bf16
__device__ __align__(16) bf16  g_wb[5 * 1024 * 1024];   // 10 MiB: weights bf16
__device__ __align__(16) bf16  g_og[16384 * 1024];      // 32 MiB: output gate
__device__ float g_cA[CH * 8192];                       // scan carries / seeds
__device__ float g_cB[CH * 8192];

__device__ inline short bfbits(float f) {  // RNE f32 -> bf16 bits
  unsigned x = __float_as_uint(f);
  return (short)((x + 0x7FFFu + ((x >> 16) & 1u)) >> 16);
}
__device__ inline float sigmoidf_(float z) { return 1.0f / (1.0f + __expf(-z)); }

__device__ inline void gload_lds16(const void* g, void* l) {
  __builtin_amdgcn_global_load_lds(
      (const __attribute__((address_space(1))) void*)g,
      (__attribute__((address_space(3))) void*)l, 16, 0, 0);
}

// ---- f32 -> bf16 bulk convert (vec4, grid-stride) ------------------------
__global__ void conv_kernel(const float* __restrict__ src, bf16* __restrict__ dst, int n4) {
  int i = blockIdx.x * blockDim.x + threadIdx.x;
  const int stride = gridDim.x * blockDim.x;
  for (; i < n4; i += stride) {
    f32x4 v = ((const f32x4*)src)[i];
    s16x4 w;
    w[0] = bfbits(v[0]); w[1] = bfbits(v[1]);
    w[2] = bfbits(v[2]); w[3] = bfbits(v[3]);
    ((s16x4*)dst)[i] = w;
  }
}

// ===========================================================================
// Pipelined dual GEMM sharing A: acc1 = A@B1^T, acc2 = A@B2^T
//   - double-buffered LDS (BK2=32), prefetch(t+1) issued before compute(t),
//     ONE __syncthreads per step (its vmcnt/lgkmcnt drain is the pipeline wait)
//   - T2 XOR swizzle: LDS slot (row, chunk) holds global (row, chunk ^ ((row>>1)&3));
//     achieved by pre-swizzling the per-lane GLOBAL source address (LDS dest stays
//     linear for global_load_lds), and XOR-ing the ds_read chunk index.
//     8-way bank conflict -> 2-way (free).
// DM=0: C1(float) = sigmoid(acc1+b1); C2(bf16) = sigmoid(acc2+b2)   [r, og]
// DM=1: C1(bf16)  = acc1 * sigmoid(acc2+b2); C2 unused              [xi]
// ===========================================================================
template <int DM>
__global__ __launch_bounds__(256, 3) void gemm_dual(
    const bf16* __restrict__ A, const bf16* __restrict__ B1,
    const bf16* __restrict__ B2, const float* __restrict__ bias1,
    const float* __restrict__ bias2, void* __restrict__ C1,
    bf16* __restrict__ C2, int M, int N, int K)
{
  __shared__ bf16 As [2][TM * BK2];
  __shared__ bf16 Bs1[2][TN * BK2];
  __shared__ bf16 Bs2[2][TN * BK2];

  const int tid  = threadIdx.x;
  const int wave = tid >> 6;
  const int lane = tid & 63;
  const int m0 = blockIdx.x * TM;
  const int n0 = blockIdx.y * TN;
  const int wm = (wave >> 1) * 64;
  const int wn = (wave & 1) * 64;

  // ---- staging addressing (loop-invariant) ----
  // per gload instruction: 64 lanes x 16B = 16 rows x 64B; lane l -> row +(l>>2), 16B-chunk (l&3)
  // source chunk pre-swizzled: chunk ^ ((row>>1)&3) == (l&3) ^ ((l>>3)&3)  (row = q*16 + (l>>2))
  const int srow = lane >> 2;
  const int schk = ((lane & 3) ^ ((lane >> 3) & 3)) << 3;   // element offset
  const bf16* pA  = A  + (size_t)(m0 + wave * 32 + srow) * K + schk;
  const bf16* pB1 = B1 + (size_t)(n0 + wave * 32 + srow) * K + schk;
  const bf16* pB2 = B2 + (size_t)(n0 + wave * 32 + srow) * K + schk;
  const size_t krow16 = (size_t)16 * K;
  const int l0 = wave * 1024;        // LDS element base (2 instr x 512 elems per wave)

  // ---- ds_read offsets (loop-invariant, swizzled) ----
  const int lane15 = lane & 15;
  const int csel   = lane >> 4;      // which 16B chunk of the 64B row
  int aOff[4], bOff[4];
  #pragma unroll
  for (int i = 0; i < 4; ++i) {
    const int Ra = wm + i * 16 + lane15;
    aOff[i] = Ra * BK2 + ((csel ^ ((Ra >> 1) & 3)) << 3);
    const int Rb = wn + i * 16 + lane15;
    bOff[i] = Rb * BK2 + ((csel ^ ((Rb >> 1) & 3)) << 3);
  }

  f32x4 acc1[4][4] = {};
  f32x4 acc2[4][4] = {};

  #define STAGE_D(buf, koff)                                                 \
    do {                                                                     \
      gload_lds16(pA  + (koff),          (void*)&As [buf][l0]);              \
      gload_lds16(pB1 + (koff),          (void*)&Bs1[buf][l0]);              \
      gload_lds16(pB2 + (koff),          (void*)&Bs2[buf][l0]);              \
      gload_lds16(pA  + krow16 + (koff), (void*)&As [buf][l0 + 512]);        \
      gload_lds16(pB1 + krow16 + (koff), (void*)&Bs1[buf][l0 + 512]);        \
      gload_lds16(pB2 + krow16 + (koff), (void*)&Bs2[buf][l0 + 512]);        \
    } while (0)

  int cur = 0;
  STAGE_D(0, 0);
  __syncthreads();   // drains vmcnt: buf0 ready

  for (int t = 0; t < NT; ++t) {
    if (t + 1 < NT) STAGE_D(cur ^ 1, (size_t)(t + 1) * BK2);
    __builtin_amdgcn_sched_barrier(0);   // pin: stage issues stay ahead of compute
    s16x8 af[4], b1f[4], b2f[4];
    #pragma unroll
    for (int i = 0; i < 4; ++i) af[i] = *(const s16x8*)&As[cur][aOff[i]];
    #pragma unroll
    for (int j = 0; j < 4; ++j) {
      b1f[j] = *(const s16x8*)&Bs1[cur][bOff[j]];
      b2f[j] = *(const s16x8*)&Bs2[cur][bOff[j]];
    }
    __builtin_amdgcn_s_setprio(1);
    #pragma unroll
    for (int i = 0; i < 4; ++i)
      #pragma unroll
      for (int j = 0; j < 4; ++j) {
        acc1[i][j] = __builtin_amdgcn_mfma_f32_16x16x32_bf16(af[i], b1f[j], acc1[i][j], 0, 0, 0);
        acc2[i][j] = __builtin_amdgcn_mfma_f32_16x16x32_bf16(af[i], b2f[j], acc2[i][j], 0, 0, 0);
      }
    __builtin_amdgcn_s_setprio(0);
    __syncthreads();   // drain: this step's prefetch landed; all reads of buf[cur] done
    cur ^= 1;
  }
  #undef STAGE_D

  const int rq = (lane >> 4) * 4;
  const int cl = lane & 15;
  #pragma unroll
  for (int j = 0; j < 4; ++j) {
    const int gc = n0 + wn + j * 16 + cl;
    const float b2 = bias2[gc];
    float b1 = 0.0f;
    if constexpr (DM == 0) b1 = bias1[gc];
    #pragma unroll
    for (int i = 0; i < 4; ++i) {
      const int gr = m0 + wm + i * 16 + rq;
      #pragma unroll
      for (int rr = 0; rr < 4; ++rr) {
        const size_t idx = (size_t)(gr + rr) * N + gc;
        const float v1 = acc1[i][j][rr];
        const float v2 = acc2[i][j][rr];
        if constexpr (DM == 0) {
          ((float*)C1)[idx] = sigmoidf_(v1 + b1);
          C2[idx] = __float2bfloat16(sigmoidf_(v2 + b2));
        } else {
          ((bf16*)C1)[idx] = __float2bfloat16(v1 * sigmoidf_(v2 + b2));
        }
      }
    }
  }
}

// ---- pipelined single GEMM: y = z @ wo^T, bf16 in, f32 out ---------------
__global__ __launch_bounds__(256, 3) void gemm_single(
    const bf16* __restrict__ A, const bf16* __restrict__ Bw,
    float* __restrict__ C, int M, int N, int K)
{
  __shared__ bf16 As[2][TM * BK2];
  __shared__ bf16 Bs[2][TN * BK2];

  const int tid  = threadIdx.x;
  const int wave = tid >> 6;
  const int lane = tid & 63;
  const int m0 = blockIdx.x * TM;
  const int n0 = blockIdx.y * TN;
  const int wm = (wave >> 1) * 64;
  const int wn = (wave & 1) * 64;

  const int srow = lane >> 2;
  const int schk = ((lane & 3) ^ ((lane >> 3) & 3)) << 3;
  const bf16* pA = A  + (size_t)(m0 + wave * 32 + srow) * K + schk;
  const bf16* pB = Bw + (size_t)(n0 + wave * 32 + srow) * K + schk;
  const size_t krow16 = (size_t)16 * K;
  const int l0 = wave * 1024;

  const int lane15 = lane & 15;
  const int csel   = lane >> 4;
  int aOff[4], bOff[4];
  #pragma unroll
  for (int i = 0; i < 4; ++i) {
    const int Ra = wm + i * 16 + lane15;
    aOff[i] = Ra * BK2 + ((csel ^ ((Ra >> 1) & 3)) << 3);
    const int Rb = wn + i * 16 + lane15;
    bOff[i] = Rb * BK2 + ((csel ^ ((Rb >> 1) & 3)) << 3);
  }

  f32x4 acc[4][4] = {};

  #define STAGE_S(buf, koff)                                                 \
    do {                                                                     \
      gload_lds16(pA + (koff),          (void*)&As[buf][l0]);                \
      gload_lds16(pB + (koff),          (void*)&Bs[buf][l0]);                \
      gload_lds16(pA + krow16 + (koff), (void*)&As[buf][l0 + 512]);          \
      gload_lds16(pB + krow16 + (koff), (void*)&Bs[buf][l0 + 512]);          \
    } while (0)

  int cur = 0;
  STAGE_S(0, 0);
  __syncthreads();

  for (int t = 0; t < NT; ++t) {
    if (t + 1 < NT) STAGE_S(cur ^ 1, (size_t)(t + 1) * BK2);
    __builtin_amdgcn_sched_barrier(0);
    s16x8 af[4], bfr[4];
    #pragma unroll
    for (int i = 0; i < 4; ++i) af[i] = *(const s16x8*)&As[cur][aOff[i]];
    #pragma unroll
    for (int j = 0; j < 4; ++j) bfr[j] = *(const s16x8*)&Bs[cur][bOff[j]];
    __builtin_amdgcn_s_setprio(1);
    #pragma unroll
    for (int i = 0; i < 4; ++i)
      #pragma unroll
      for (int j = 0; j < 4; ++j)
        acc[i][j] = __builtin_amdgcn_mfma_f32_16x16x32_bf16(af[i], bfr[j], acc[i][j], 0, 0, 0);
    __builtin_amdgcn_s_setprio(0);
    __syncthreads();
    cur ^= 1;
  }
  #undef STAGE_S

  const int rq = (lane >> 4) * 4;
  const int cl = lane & 15;
  #pragma unroll
  for (int j = 0; j < 4; ++j) {
    const int gc = n0 + wn + j * 16 + cl;
    #pragma unroll
    for (int i = 0; i < 4; ++i) {
      const int gr = m0 + wm + i * 16 + rq;
      #pragma unroll
      for (int rr = 0; rr < 4; ++rr)
        C[(size_t)(gr + rr) * N + gc] = acc[i][j][rr];
    }
  }
}

// ---- chunked scan --------------------------------------------------------
__global__ __launch_bounds__(256) void scan_p1(
    const float* __restrict__ r, const bf16* __restrict__ xi)
{
  const int bid = blockIdx.x;                 // 0..1023
  const int c   = bid >> 5;                   // chunk
  const int idx = (bid & 31) * 256 + threadIdx.x;  // channel 0..8191
  const int b = idx >> 10, m = idx & 1023;
  const size_t base = ((size_t)b * 2048 + c * CS) * 1024 + m;
  float a = 1.0f, s = 0.0f;
  #pragma unroll 16
  for (int t = 0; t < CS; ++t) {
    const size_t o = base + (size_t)t * 1024;
    const float rv = r[o];
    const float xv = __bfloat162float(xi[o]);
    a *= rv;
    s = fmaf(s, rv, xv);
  }
  g_cA[c * 8192 + idx] = a;
  g_cB[c * 8192 + idx] = s;
}

__global__ __launch_bounds__(256) void scan_p2(
    const float* __restrict__ mem, float* __restrict__ memout)
{
  const int idx = blockIdx.x * 256 + threadIdx.x;  // 0..8191
  float H = mem[idx];
  #pragma unroll
  for (int c = 0; c < CH; ++c) {
    const float a = g_cA[c * 8192 + idx];
    const float s = g_cB[c * 8192 + idx];
    g_cA[c * 8192 + idx] = H;     // seed for chunk c
    H = fmaf(a, H, s);
  }
  memout[idx] = H;
}

__global__ __launch_bounds__(256) void scan_p3(
    const float* __restrict__ r, bf16* xi, const bf16* __restrict__ og)
{
  const int bid = blockIdx.x;
  const int c   = bid >> 5;
  const int idx = (bid & 31) * 256 + threadIdx.x;
  const int b = idx >> 10, m = idx & 1023;
  const size_t base = ((size_t)b * 2048 + c * CS) * 1024 + m;
  float h = g_cA[c * 8192 + idx];
  #pragma unroll 8
  for (int t = 0; t < CS; ++t) {
    const size_t o = base + (size_t)t * 1024;
    const float rv = r[o];
    const float xv = __bfloat162float(xi[o]);
    const float ov = __bfloat162float(og[o]);
    h = fmaf(h, rv, xv);
    xi[o] = __float2bfloat16(h / (1.0f + fabsf(h)) * ov);
  }
}

extern "C" void kernel_launch(void* const* d_in, const int* in_sizes, int n_in,
                              void* d_out, int out_size, void* d_ws, size_t ws_size,
                              hipStream_t stream)
{
  const float* x     = (const float*)d_in[0];
  const float* mem   = (const float*)d_in[1];
  const float* wr_w  = (const float*)d_in[2];
  const float* wr_b  = (const float*)d_in[3];
  const float* wi_w  = (const float*)d_in[4];
  const float* wig_w = (const float*)d_in[5];
  const float* wig_b = (const float*)d_in[6];
  const float* wog_w = (const float*)d_in[7];
  const float* wog_b = (const float*)d_in[8];
  const float* wo_w  = (const float*)d_in[9];
  float* out = (float*)d_out;

  const int M = 16384, N = 1024, K = 1024;
  const size_t MN = (size_t)M * N;

  // ws: [r f32: 64 MiB][xi bf16: 32 MiB]  (96 MiB; proven available)
  float* r  = (float*)d_ws;
  bf16*  xi = (bf16*)((char*)d_ws + MN * 4);

  bf16* xb = nullptr, *wb = nullptr, *og = nullptr;
  hipGetSymbolAddress((void**)&xb, HIP_SYMBOL(g_xb));
  hipGetSymbolAddress((void**)&wb, HIP_SYMBOL(g_wb));
  hipGetSymbolAddress((void**)&og, HIP_SYMBOL(g_og));

  dim3 block(256);

  // 1) convert x and 5 weights to bf16
  conv_kernel<<<dim3(2048), block, 0, stream>>>(x, xb, (int)(MN / 4));
  const int W4 = 1024 * 1024 / 4;
  conv_kernel<<<dim3(256), block, 0, stream>>>(wr_w,  wb + 0 * 1024 * 1024, W4);
  conv_kernel<<<dim3(256), block, 0, stream>>>(wi_w,  wb + 1 * 1024 * 1024, W4);
  conv_kernel<<<dim3(256), block, 0, stream>>>(wig_w, wb + 2 * 1024 * 1024, W4);
  conv_kernel<<<dim3(256), block, 0, stream>>>(wog_w, wb + 3 * 1024 * 1024, W4);
  conv_kernel<<<dim3(256), block, 0, stream>>>(wo_w,  wb + 4 * 1024 * 1024, W4);

  dim3 grid(M / TM, N / TN);
  // 2) r = sigmoid(x@wr^T+b), og = sigmoid(x@wog^T+b)
  gemm_dual<0><<<grid, block, 0, stream>>>(xb, wb + 0 * 1024 * 1024, wb + 3 * 1024 * 1024,
                                           wr_b, wog_b, r, og, M, N, K);
  // 3) xi = (x@wi^T) * sigmoid(x@wig^T+b)
  gemm_dual<1><<<grid, block, 0, stream>>>(xb, wb + 1 * 1024 * 1024, wb + 2 * 1024 * 1024,
                                           nullptr, wig_b, xi, nullptr, M, N, K);
  // 4) chunked scan; z in-place over xi; mem_out -> out tail (f32)
  scan_p1<<<dim3(1024), block, 0, stream>>>(r, xi);
  scan_p2<<<dim3(32),   block, 0, stream>>>(mem, out + MN);
  scan_p3<<<dim3(1024), block, 0, stream>>>(r, xi, og);
  // 5) y = z @ wo^T
  gemm_single<<<grid, block, 0, stream>>>(xi, wb + 4 * 1024 * 1024, out, M, N, K);
}

// Round 2
// 489.663 us; speedup vs baseline: 1.4847x; 1.4847x over previous
//
#include <hip/hip_runtime.h>
#include <hip/hip_bf16.h>
#include <cstdint>
#include <cstddef>

using bf16 = __hip_bfloat16;

typedef short s16x8 __attribute__((ext_vector_type(8)));
typedef short s16x4 __attribute__((ext_vector_type(4)));
typedef float f32x4 __attribute__((ext_vector_type(4)));

#define TM 128
#define TN 128
#define BK2 32          // K per pipeline step
#define NT 32           // K / BK2
#define CH 32           // scan chunks
#define CS 64           // steps per chunk (CH*CS = 2048)

// ---- static device scratch (sidesteps unknown ws_size) -------------------
__device__ __align__(16) bf16  g_xb[16384 * 1024];      // 32 MiB: x in bf16
__device__ __align__(16) bf16  g_wb[5 * 1024 * 1024];   // 10 MiB: weights bf16
__device__ __align__(16) bf16  g_og[16384 * 1024];      // 32 MiB: output gate
__device__ float g_cA[CH * 8192];                       // scan carries / seeds
__device__ float g_cB[CH * 8192];

__device__ inline short bfbits(float f) {  // RNE f32 -> bf16 bits
  unsigned x = __float_as_uint(f);
  return (short)((x + 0x7FFFu + ((x >> 16) & 1u)) >> 16);
}
__device__ inline float sigmoidf_(float z) { return 1.0f / (1.0f + __expf(-z)); }

__device__ inline void gload_lds16(const void* g, void* l) {
  __builtin_amdgcn_global_load_lds(
      (const __attribute__((address_space(1))) void*)g,
      (__attribute__((address_space(3))) void*)l, 16, 0, 0);
}

// ---- f32 -> bf16 bulk convert (vec4, grid-stride) ------------------------
__global__ void conv_kernel(const float* __restrict__ src, bf16* __restrict__ dst, int n4) {
  int i = blockIdx.x * blockDim.x + threadIdx.x;
  const int stride = gridDim.x * blockDim.x;
  for (; i < n4; i += stride) {
    f32x4 v = ((const f32x4*)src)[i];
    s16x4 w;
    w[0] = bfbits(v[0]); w[1] = bfbits(v[1]);
    w[2] = bfbits(v[2]); w[3] = bfbits(v[3]);
    ((s16x4*)dst)[i] = w;
  }
}

// ===========================================================================
// 2-deep pipelined dual GEMM sharing A: acc1 = A@B1^T, acc2 = A@B2^T
//   - 3 LDS buffers (BK2=32): at iter t, stage tile t+2 while computing tile t,
//     with tile t+1 already in flight from the previous iteration.
//   - T4 counted waits: s_waitcnt vmcnt(6) before a RAW s_barrier — the newest
//     stage (6 loads/wave) stays in flight across the barrier; only the oldest
//     6 (tile t+1) must land. Never vmcnt(0) until the epilogue.
//     Safety: vmcnt is per-wave; each wave covers its own 6 tile-(t+1) loads,
//     so after the barrier the whole tile is resident. Buffer overwritten by
//     stage(t) is buf[(t-1)%3], whose readers consumed it (lgkmcnt before
//     MFMA) before the iter-(t-1) barrier.
//   - T2 XOR swizzle via pre-swizzled GLOBAL source (LDS dest stays linear for
//     global_load_lds) + XOR-ed ds_read chunk: bank conflicts measured 0.
//   - __launch_bounds__(256,2): 256-reg cap fits the ~220-reg live set
//     (round-1's (256,3)=170 cap spilled: VGPR 84, WRITE_SIZE 3.3x).
// DM=0: C1(float) = sigmoid(acc1+b1); C2(bf16) = sigmoid(acc2+b2)   [r, og]
// DM=1: C1(bf16)  = acc1 * sigmoid(acc2+b2); C2 unused              [xi]
// ===========================================================================
template <int DM>
__global__ __launch_bounds__(256, 2) void gemm_dual(
    const bf16* __restrict__ A, const bf16* __restrict__ B1,
    const bf16* __restrict__ B2, const float* __restrict__ bias1,
    const float* __restrict__ bias2, void* __restrict__ C1,
    bf16* __restrict__ C2, int M, int N, int K)
{
  __shared__ bf16 As [3][TM * BK2];
  __shared__ bf16 Bs1[3][TN * BK2];
  __shared__ bf16 Bs2[3][TN * BK2];

  const int tid  = threadIdx.x;
  const int wave = tid >> 6;
  const int lane = tid & 63;
  const int m0 = blockIdx.x * TM;
  const int n0 = blockIdx.y * TN;
  const int wm = (wave >> 1) * 64;
  const int wn = (wave & 1) * 64;

  // ---- staging addressing (loop-invariant) ----
  // per gload instruction: 64 lanes x 16B = 16 rows x 64B; lane l -> row +(l>>2), chunk (l&3)
  // source chunk pre-swizzled: chunk ^ ((row>>1)&3) == (l&3) ^ ((l>>3)&3)
  const int srow = lane >> 2;
  const int schk = ((lane & 3) ^ ((lane >> 3) & 3)) << 3;   // element offset
  const bf16* pA  = A  + (size_t)(m0 + wave * 32 + srow) * K + schk;
  const bf16* pB1 = B1 + (size_t)(n0 + wave * 32 + srow) * K + schk;
  const bf16* pB2 = B2 + (size_t)(n0 + wave * 32 + srow) * K + schk;
  const size_t krow16 = (size_t)16 * K;
  const int l0 = wave * 1024;        // LDS element base (2 instr x 512 elems per wave)

  // ---- ds_read offsets (loop-invariant, swizzled) ----
  const int lane15 = lane & 15;
  const int csel   = lane >> 4;      // which 16B chunk of the 64B row
  int aOff[4], bOff[4];
  #pragma unroll
  for (int i = 0; i < 4; ++i) {
    const int Ra = wm + i * 16 + lane15;
    aOff[i] = Ra * BK2 + ((csel ^ ((Ra >> 1) & 3)) << 3);
    const int Rb = wn + i * 16 + lane15;
    bOff[i] = Rb * BK2 + ((csel ^ ((Rb >> 1) & 3)) << 3);
  }

  f32x4 acc1[4][4] = {};
  f32x4 acc2[4][4] = {};

  auto stage = [&](int buf, size_t koff) {
    gload_lds16(pA  + koff,          (void*)&As [buf][l0]);
    gload_lds16(pB1 + koff,          (void*)&Bs1[buf][l0]);
    gload_lds16(pB2 + koff,          (void*)&Bs2[buf][l0]);
    gload_lds16(pA  + krow16 + koff, (void*)&As [buf][l0 + 512]);
    gload_lds16(pB1 + krow16 + koff, (void*)&Bs1[buf][l0 + 512]);
    gload_lds16(pB2 + krow16 + koff, (void*)&Bs2[buf][l0 + 512]);
  };

  // prologue: tiles 0 and 1 in flight; wait only for tile 0 (oldest 6)
  stage(0, 0);
  stage(1, BK2);
  asm volatile("s_waitcnt vmcnt(6)" ::: "memory");
  __builtin_amdgcn_s_barrier();
  __builtin_amdgcn_sched_barrier(0);

  int cur = 0, nxt = 2;
  for (int t = 0; t < NT; ++t) {
    const bool pf = (t + 2 < NT);
    if (pf) stage(nxt, (size_t)(t + 2) * BK2);
    __builtin_amdgcn_sched_barrier(0);   // stage issues stay ahead of compute

    s16x8 af[4], b1f[4], b2f[4];
    const bf16* Ab  = &As [cur][0];
    const bf16* B1b = &Bs1[cur][0];
    const bf16* B2b = &Bs2[cur][0];
    #pragma unroll
    for (int i = 0; i < 4; ++i) af[i] = *(const s16x8*)&Ab[aOff[i]];
    #pragma unroll
    for (int j = 0; j < 4; ++j) {
      b1f[j] = *(const s16x8*)&B1b[bOff[j]];
      b2f[j] = *(const s16x8*)&B2b[bOff[j]];
    }
    __builtin_amdgcn_s_setprio(1);
    #pragma unroll
    for (int i = 0; i < 4; ++i)
      #pragma unroll
      for (int j = 0; j < 4; ++j) {
        acc1[i][j] = __builtin_amdgcn_mfma_f32_16x16x32_bf16(af[i], b1f[j], acc1[i][j], 0, 0, 0);
        acc2[i][j] = __builtin_amdgcn_mfma_f32_16x16x32_bf16(af[i], b2f[j], acc2[i][j], 0, 0, 0);
      }
    __builtin_amdgcn_s_setprio(0);

    // tile t+1 must be resident before next iteration reads it
    if (pf) asm volatile("s_waitcnt vmcnt(6)" ::: "memory");
    else    asm volatile("s_waitcnt vmcnt(0)" ::: "memory");
    __builtin_amdgcn_s_barrier();
    __builtin_amdgcn_sched_barrier(0);   // pin next iter's ds_reads behind barrier

    cur = (cur + 1 == 3) ? 0 : cur + 1;
    nxt = (nxt + 1 == 3) ? 0 : nxt + 1;
  }

  const int rq = (lane >> 4) * 4;
  const int cl = lane & 15;
  #pragma unroll
  for (int j = 0; j < 4; ++j) {
    const int gc = n0 + wn + j * 16 + cl;
    const float b2 = bias2[gc];
    float b1 = 0.0f;
    if constexpr (DM == 0) b1 = bias1[gc];
    #pragma unroll
    for (int i = 0; i < 4; ++i) {
      const int gr = m0 + wm + i * 16 + rq;
      #pragma unroll
      for (int rr = 0; rr < 4; ++rr) {
        const size_t idx = (size_t)(gr + rr) * N + gc;
        const float v1 = acc1[i][j][rr];
        const float v2 = acc2[i][j][rr];
        if constexpr (DM == 0) {
          ((float*)C1)[idx] = sigmoidf_(v1 + b1);
          C2[idx] = __float2bfloat16(sigmoidf_(v2 + b2));
        } else {
          ((bf16*)C1)[idx] = __float2bfloat16(v1 * sigmoidf_(v2 + b2));
        }
      }
    }
  }
}

// ---- 2-deep pipelined single GEMM: y = z @ wo^T, bf16 in, f32 out --------
// live set ~130 regs -> (256,3)'s 170-reg cap is safe; 48 KiB LDS -> 3 blocks/CU
__global__ __launch_bounds__(256, 3) void gemm_single(
    const bf16* __restrict__ A, const bf16* __restrict__ Bw,
    float* __restrict__ C, int M, int N, int K)
{
  __shared__ bf16 As[3][TM * BK2];
  __shared__ bf16 Bs[3][TN * BK2];

  const int tid  = threadIdx.x;
  const int wave = tid >> 6;
  const int lane = tid & 63;
  const int m0 = blockIdx.x * TM;
  const int n0 = blockIdx.y * TN;
  const int wm = (wave >> 1) * 64;
  const int wn = (wave & 1) * 64;

  const int srow = lane >> 2;
  const int schk = ((lane & 3) ^ ((lane >> 3) & 3)) << 3;
  const bf16* pA = A  + (size_t)(m0 + wave * 32 + srow) * K + schk;
  const bf16* pB = Bw + (size_t)(n0 + wave * 32 + srow) * K + schk;
  const size_t krow16 = (size_t)16 * K;
  const int l0 = wave * 1024;

  const int lane15 = lane & 15;
  const int csel   = lane >> 4;
  int aOff[4], bOff[4];
  #pragma unroll
  for (int i = 0; i < 4; ++i) {
    const int Ra = wm + i * 16 + lane15;
    aOff[i] = Ra * BK2 + ((csel ^ ((Ra >> 1) & 3)) << 3);
    const int Rb = wn + i * 16 + lane15;
    bOff[i] = Rb * BK2 + ((csel ^ ((Rb >> 1) & 3)) << 3);
  }

  f32x4 acc[4][4] = {};

  auto stage = [&](int buf, size_t koff) {
    gload_lds16(pA + koff,          (void*)&As[buf][l0]);
    gload_lds16(pB + koff,          (void*)&Bs[buf][l0]);
    gload_lds16(pA + krow16 + koff, (void*)&As[buf][l0 + 512]);
    gload_lds16(pB + krow16 + koff, (void*)&Bs[buf][l0 + 512]);
  };

  stage(0, 0);
  stage(1, BK2);
  asm volatile("s_waitcnt vmcnt(4)" ::: "memory");
  __builtin_amdgcn_s_barrier();
  __builtin_amdgcn_sched_barrier(0);

  int cur = 0, nxt = 2;
  for (int t = 0; t < NT; ++t) {
    const bool pf = (t + 2 < NT);
    if (pf) stage(nxt, (size_t)(t + 2) * BK2);
    __builtin_amdgcn_sched_barrier(0);

    s16x8 af[4], bfr[4];
    const bf16* Ab = &As[cur][0];
    const bf16* Bb = &Bs[cur][0];
    #pragma unroll
    for (int i = 0; i < 4; ++i) af[i] = *(const s16x8*)&Ab[aOff[i]];
    #pragma unroll
    for (int j = 0; j < 4; ++j) bfr[j] = *(const s16x8*)&Bb[bOff[j]];
    __builtin_amdgcn_s_setprio(1);
    #pragma unroll
    for (int i = 0; i < 4; ++i)
      #pragma unroll
      for (int j = 0; j < 4; ++j)
        acc[i][j] = __builtin_amdgcn_mfma_f32_16x16x32_bf16(af[i], bfr[j], acc[i][j], 0, 0, 0);
    __builtin_amdgcn_s_setprio(0);

    if (pf) asm volatile("s_waitcnt vmcnt(4)" ::: "memory");
    else    asm volatile("s_waitcnt vmcnt(0)" ::: "memory");
    __builtin_amdgcn_s_barrier();
    __builtin_amdgcn_sched_barrier(0);

    cur = (cur + 1 == 3) ? 0 : cur + 1;
    nxt = (nxt + 1 == 3) ? 0 : nxt + 1;
  }

  const int rq = (lane >> 4) * 4;
  const int cl = lane & 15;
  #pragma unroll
  for (int j = 0; j < 4; ++j) {
    const int gc = n0 + wn + j * 16 + cl;
    #pragma unroll
    for (int i = 0; i < 4; ++i) {
      const int gr = m0 + wm + i * 16 + rq;
      #pragma unroll
      for (int rr = 0; rr < 4; ++rr)
        C[(size_t)(gr + rr) * N + gc] = acc[i][j][rr];
    }
  }
}

// ---- chunked scan --------------------------------------------------------
__global__ __launch_bounds__(256) void scan_p1(
    const float* __restrict__ r, const bf16* __restrict__ xi)
{
  const int bid = blockIdx.x;                 // 0..1023
  const int c   = bid >> 5;                   // chunk
  const int idx = (bid & 31) * 256 + threadIdx.x;  // channel 0..8191
  const int b = idx >> 10, m = idx & 1023;
  const size_t base = ((size_t)b * 2048 + c * CS) * 1024 + m;
  float a = 1.0f, s = 0.0f;
  #pragma unroll 16
  for (int t = 0; t < CS; ++t) {
    const size_t o = base + (size_t)t * 1024;
    const float rv = r[o];
    const float xv = __bfloat162float(xi[o]);
    a *= rv;
    s = fmaf(s, rv, xv);
  }
  g_cA[c * 8192 + idx] = a;
  g_cB[c * 8192 + idx] = s;
}

__global__ __launch_bounds__(256) void scan_p2(
    const float* __restrict__ mem, float* __restrict__ memout)
{
  const int idx = blockIdx.x * 256 + threadIdx.x;  // 0..8191
  float H = mem[idx];
  #pragma unroll
  for (int c = 0; c < CH; ++c) {
    const float a = g_cA[c * 8192 + idx];
    const float s = g_cB[c * 8192 + idx];
    g_cA[c * 8192 + idx] = H;     // seed for chunk c
    H = fmaf(a, H, s);
  }
  memout[idx] = H;
}

__global__ __launch_bounds__(256) void scan_p3(
    const float* __restrict__ r, bf16* xi, const bf16* __restrict__ og)
{
  const int bid = blockIdx.x;
  const int c   = bid >> 5;
  const int idx = (bid & 31) * 256 + threadIdx.x;
  const int b = idx >> 10, m = idx & 1023;
  const size_t base = ((size_t)b * 2048 + c * CS) * 1024 + m;
  float h = g_cA[c * 8192 + idx];
  #pragma unroll 8
  for (int t = 0; t < CS; ++t) {
    const size_t o = base + (size_t)t * 1024;
    const float rv = r[o];
    const float xv = __bfloat162float(xi[o]);
    const float ov = __bfloat162float(og[o]);
    h = fmaf(h, rv, xv);
    xi[o] = __float2bfloat16(h / (1.0f + fabsf(h)) * ov);
  }
}

extern "C" void kernel_launch(void* const* d_in, const int* in_sizes, int n_in,
                              void* d_out, int out_size, void* d_ws, size_t ws_size,
                              hipStream_t stream)
{
  const float* x     = (const float*)d_in[0];
  const float* mem   = (const float*)d_in[1];
  const float* wr_w  = (const float*)d_in[2];
  const float* wr_b  = (const float*)d_in[3];
  const float* wi_w  = (const float*)d_in[4];
  const float* wig_w = (const float*)d_in[5];
  const float* wig_b = (const float*)d_in[6];
  const float* wog_w = (const float*)d_in[7];
  const float* wog_b = (const float*)d_in[8];
  const float* wo_w  = (const float*)d_in[9];
  float* out = (float*)d_out;

  const int M = 16384, N = 1024, K = 1024;
  const size_t MN = (size_t)M * N;

  // ws: [r f32: 64 MiB][xi bf16: 32 MiB]  (96 MiB; proven available)
  float* r  = (float*)d_ws;
  bf16*  xi = (bf16*)((char*)d_ws + MN * 4);

  bf16* xb = nullptr, *wb = nullptr, *og = nullptr;
  hipGetSymbolAddress((void**)&xb, HIP_SYMBOL(g_xb));
  hipGetSymbolAddress((void**)&wb, HIP_SYMBOL(g_wb));
  hipGetSymbolAddress((void**)&og, HIP_SYMBOL(g_og));

  dim3 block(256);

  // 1) convert x and 5 weights to bf16
  conv_kernel<<<dim3(2048), block, 0, stream>>>(x, xb, (int)(MN / 4));
  const int W4 = 1024 * 1024 / 4;
  conv_kernel<<<dim3(256), block, 0, stream>>>(wr_w,  wb + 0 * 1024 * 1024, W4);
  conv_kernel<<<dim3(256), block, 0, stream>>>(wi_w,  wb + 1 * 1024 * 1024, W4);
  conv_kernel<<<dim3(256), block, 0, stream>>>(wig_w, wb + 2 * 1024 * 1024, W4);
  conv_kernel<<<dim3(256), block, 0, stream>>>(wog_w, wb + 3 * 1024 * 1024, W4);
  conv_kernel<<<dim3(256), block, 0, stream>>>(wo_w,  wb + 4 * 1024 * 1024, W4);

  dim3 grid(M / TM, N / TN);
  // 2) r = sigmoid(x@wr^T+b), og = sigmoid(x@wog^T+b)
  gemm_dual<0><<<grid, block, 0, stream>>>(xb, wb + 0 * 1024 * 1024, wb + 3 * 1024 * 1024,
                                           wr_b, wog_b, r, og, M, N, K);
  // 3) xi = (x@wi^T) * sigmoid(x@wig^T+b)
  gemm_dual<1><<<grid, block, 0, stream>>>(xb, wb + 1 * 1024 * 1024, wb + 2 * 1024 * 1024,
                                           nullptr, wig_b, xi, nullptr, M, N, K);
  // 4) chunked scan; z in-place over xi; mem_out -> out tail (f32)
  scan_p1<<<dim3(1024), block, 0, stream>>>(r, xi);
  scan_p2<<<dim3(32),   block, 0, stream>>>(mem, out + MN);
  scan_p3<<<dim3(1024), block, 0, stream>>>(r, xi, og);
  // 5) y = z @ wo^T
  gemm_single<<<grid, block, 0, stream>>>(xi, wb + 4 * 1024 * 1024, out, M, N, K);
}

// Round 3
// 452.997 us; speedup vs baseline: 1.6049x; 1.0809x over previous
//
#include <hip/hip_runtime.h>
#include <hip/hip_bf16.h>
#include <cstdint>
#include <cstddef>

using bf16 = __hip_bfloat16;

typedef short s16x8 __attribute__((ext_vector_type(8)));
typedef short s16x4 __attribute__((ext_vector_type(4)));
typedef float f32x4 __attribute__((ext_vector_type(4)));

#define CH 32           // scan chunks
#define CS 64           // steps per chunk (CH*CS = 2048)

// ---- static device scratch (sidesteps unknown ws_size) -------------------
__device__ __align__(16) bf16  g_xb[16384 * 1024];      // 32 MiB: x in bf16
__device__ __align__(16) bf16  g_wb[5 * 1024 * 1024];   // 10 MiB: weights bf16
__device__ __align__(16) bf16  g_og[16384 * 1024];      // 32 MiB: output gate
__device__ float g_cA[CH * 8192];                       // scan carries / seeds
__device__ float g_cB[CH * 8192];

__device__ inline short bfbits(float f) {  // RNE f32 -> bf16 bits
  unsigned x = __float_as_uint(f);
  return (short)((x + 0x7FFFu + ((x >> 16) & 1u)) >> 16);
}
__device__ inline float sigmoidf_(float z) { return 1.0f / (1.0f + __expf(-z)); }

__device__ inline void gload_lds16(const void* g, void* l) {
  __builtin_amdgcn_global_load_lds(
      (const __attribute__((address_space(1))) void*)g,
      (__attribute__((address_space(3))) void*)l, 16, 0, 0);
}

// ---- f32 -> bf16 bulk convert (vec4, grid-stride) ------------------------
__global__ void conv_kernel(const float* __restrict__ src, bf16* __restrict__ dst, int n4) {
  int i = blockIdx.x * blockDim.x + threadIdx.x;
  const int stride = gridDim.x * blockDim.x;
  for (; i < n4; i += stride) {
    f32x4 v = ((const f32x4*)src)[i];
    s16x4 w;
    w[0] = bfbits(v[0]); w[1] = bfbits(v[1]);
    w[2] = bfbits(v[2]); w[3] = bfbits(v[3]);
    ((s16x4*)dst)[i] = w;
  }
}

// ===========================================================================
// QUAD GEMM: all four projections in one pass, sharing the A (x) operand.
//   TM=256, TN=64, BK=64, 512 threads (8 waves), 1 block/CU.
//   waves 0-3: pair {B0=wr, B1=wog} -> r = sigmoid(.+b), og = sigmoid(.+b)
//   waves 4-7: pair {B2=wi, B3=wig} -> xi = lin * sigmoid(gate+b)
//   Each wave: 64x64 output tile per matrix of its pair -> acc 2x16 f32x4,
//   64 MFMA per K-step (vs 32 in the old dual) -> half the barrier-walls.
//   Double-buffered LDS 2 x (A 32KB + 4xB 8KB) = 128 KB; stage(t+1) issued
//   before compute(t); vmcnt(0)+s_barrier once per wall. Buffer reuse is
//   safe: compiler lgkmcnt before each MFMA completes the wave's ds_reads
//   before it can reach the barrier.
//   Swizzle (rows are 128B): LDS slot (row, c16) holds global chunk
//   c16 ^ (row&7); applied on the global source (LDS dest linear for
//   global_load_lds) and on the ds_read chunk. 16-way -> 2-way (free).
//   K order: t*64 + kk*32 ascending == old 32-step order -> bitwise-identical.
// ===========================================================================
__global__ __launch_bounds__(512, 2) void gemm_quad(
    const bf16* __restrict__ A,
    const bf16* __restrict__ B0, const bf16* __restrict__ B1,
    const bf16* __restrict__ B2, const bf16* __restrict__ B3,
    const float* __restrict__ bias_r, const float* __restrict__ bias_og,
    const float* __restrict__ bias_ig,
    float* __restrict__ Cr, bf16* __restrict__ Cog, bf16* __restrict__ Cxi,
    int M, int N, int K)
{
  __shared__ bf16 As[2][256 * 64];      // 64 KB
  __shared__ bf16 Bs[2][4][64 * 64];    // 64 KB

  const int tid  = threadIdx.x;
  const int wave = tid >> 6;            // 0..7
  const int lane = tid & 63;
  const int m0 = blockIdx.x * 256;
  const int n0 = blockIdx.y * 64;

  // ---- staging addressing: 1 instr = 64 lanes x 16B = 8 rows x 8 chunks --
  const int srow8 = lane >> 3;                          // 0..7
  const int schk8 = ((lane & 7) ^ ((lane >> 3) & 7)) << 3;  // pre-swizzled src chunk
  const bf16* Bm = (wave < 2) ? B0 : (wave < 4) ? B1 : (wave < 6) ? B2 : B3;
  const bf16* pAs = A  + (size_t)(m0 + wave * 32 + srow8) * K + schk8;
  const bf16* pBs = Bm + (size_t)(n0 + (wave & 1) * 32 + srow8) * K + schk8;

  // ---- ds_read swizzled base offsets (compile-time i/j deltas on top) ----
  const int lane15 = lane & 15;
  const int csel   = lane >> 4;         // 0..3
  int o[2];
  #pragma unroll
  for (int kk = 0; kk < 2; ++kk)
    o[kk] = lane15 * 64 + ((((kk << 2) + csel) ^ (lane15 & 7)) << 3);
  const int wmA = (wave & 3) * 4096;    // (wave&3)*64 rows * 64 cols
  const int mlo = (wave >> 2) * 2;      // 0 (waves 0-3) or 2 (waves 4-7)

  f32x4 accP[4][4] = {};   // mat mlo   (r  or lin)
  f32x4 accQ[4][4] = {};   // mat mlo+1 (og or gate)

  auto stage = [&](int b, size_t koff) {
    #pragma unroll
    for (int q = 0; q < 4; ++q) {
      gload_lds16(pAs + (size_t)q * 8 * K + koff,
                  (void*)&As[b][wave * 2048 + q * 512]);
      gload_lds16(pBs + (size_t)q * 8 * K + koff,
                  (void*)&Bs[b][wave >> 1][(wave & 1) * 2048 + q * 512]);
    }
  };

  int buf = 0;
  stage(0, 0);
  asm volatile("s_waitcnt vmcnt(0)" ::: "memory");
  __builtin_amdgcn_s_barrier();
  __builtin_amdgcn_sched_barrier(0);

  for (int t = 0; t < 16; ++t) {
    if (t + 1 < 16) stage(buf ^ 1, (size_t)(t + 1) * 64);
    __builtin_amdgcn_sched_barrier(0);   // stage issues stay ahead of compute

    #pragma unroll
    for (int kk = 0; kk < 2; ++kk) {
      const bf16* aB  = &As[buf][wmA + o[kk]];
      const bf16* b0B = &Bs[buf][mlo][o[kk]];
      const bf16* b1B = &Bs[buf][mlo + 1][o[kk]];
      s16x8 af[4], f0[4], f1[4];
      #pragma unroll
      for (int i = 0; i < 4; ++i) af[i] = *(const s16x8*)(aB + i * 1024);
      #pragma unroll
      for (int j = 0; j < 4; ++j) {
        f0[j] = *(const s16x8*)(b0B + j * 1024);
        f1[j] = *(const s16x8*)(b1B + j * 1024);
      }
      __builtin_amdgcn_s_setprio(1);
      #pragma unroll
      for (int i = 0; i < 4; ++i)
        #pragma unroll
        for (int j = 0; j < 4; ++j) {
          accP[i][j] = __builtin_amdgcn_mfma_f32_16x16x32_bf16(af[i], f0[j], accP[i][j], 0, 0, 0);
          accQ[i][j] = __builtin_amdgcn_mfma_f32_16x16x32_bf16(af[i], f1[j], accQ[i][j], 0, 0, 0);
        }
      __builtin_amdgcn_s_setprio(0);
    }

    asm volatile("s_waitcnt vmcnt(0)" ::: "memory");
    __builtin_amdgcn_s_barrier();
    __builtin_amdgcn_sched_barrier(0);
    buf ^= 1;
  }

  // ---- epilogue ----
  const int rq = (lane >> 4) * 4;
  const int cl = lane & 15;
  const int wr0 = m0 + (wave & 3) * 64;
  if (wave < 4) {
    #pragma unroll
    for (int j = 0; j < 4; ++j) {
      const int gc = n0 + j * 16 + cl;
      const float bR = bias_r[gc];
      const float bO = bias_og[gc];
      #pragma unroll
      for (int i = 0; i < 4; ++i) {
        const int gr = wr0 + i * 16 + rq;
        #pragma unroll
        for (int rr = 0; rr < 4; ++rr) {
          const size_t idx = (size_t)(gr + rr) * N + gc;
          Cr[idx]  = sigmoidf_(accP[i][j][rr] + bR);
          Cog[idx] = __float2bfloat16(sigmoidf_(accQ[i][j][rr] + bO));
        }
      }
    }
  } else {
    #pragma unroll
    for (int j = 0; j < 4; ++j) {
      const int gc = n0 + j * 16 + cl;
      const float bG = bias_ig[gc];
      #pragma unroll
      for (int i = 0; i < 4; ++i) {
        const int gr = wr0 + i * 16 + rq;
        #pragma unroll
        for (int rr = 0; rr < 4; ++rr) {
          const size_t idx = (size_t)(gr + rr) * N + gc;
          Cxi[idx] = __float2bfloat16(accP[i][j][rr] * sigmoidf_(accQ[i][j][rr] + bG));
        }
      }
    }
  }
}

// ===========================================================================
// gemm_single: y = z @ wo^T.  TM=256, TN=128, BK=64, 512 threads (8 waves),
// wave grid 4Mx2N (64x64 per wave, 32 MFMA/step), triple-buffered LDS
// 3 x 48KB = 144 KB, prefetch distance 2 with counted vmcnt(6).
// 32 barrier-walls total (vs 128 in the old 128x128/BK32 version).
// ===========================================================================
__global__ __launch_bounds__(512, 2) void gemm_single(
    const bf16* __restrict__ A, const bf16* __restrict__ Bw,
    float* __restrict__ C, int M, int N, int K)
{
  __shared__ bf16 As[3][256 * 64];   // 96 KB
  __shared__ bf16 Bs[3][128 * 64];   // 48 KB

  const int tid  = threadIdx.x;
  const int wave = tid >> 6;
  const int lane = tid & 63;
  const int m0 = blockIdx.x * 256;
  const int n0 = blockIdx.y * 128;
  const int wm = (wave >> 1) * 64;
  const int wn = (wave & 1) * 64;

  const int srow8 = lane >> 3;
  const int schk8 = ((lane & 7) ^ ((lane >> 3) & 7)) << 3;
  const bf16* pAs = A  + (size_t)(m0 + wave * 32 + srow8) * K + schk8;
  const bf16* pBs = Bw + (size_t)(n0 + wave * 16 + srow8) * K + schk8;

  const int lane15 = lane & 15;
  const int csel   = lane >> 4;
  int o[2];
  #pragma unroll
  for (int kk = 0; kk < 2; ++kk)
    o[kk] = lane15 * 64 + ((((kk << 2) + csel) ^ (lane15 & 7)) << 3);

  f32x4 acc[4][4] = {};

  auto stage = [&](int b, size_t koff) {
    #pragma unroll
    for (int q = 0; q < 4; ++q)
      gload_lds16(pAs + (size_t)q * 8 * K + koff,
                  (void*)&As[b][wave * 2048 + q * 512]);
    #pragma unroll
    for (int q = 0; q < 2; ++q)
      gload_lds16(pBs + (size_t)q * 8 * K + koff,
                  (void*)&Bs[b][wave * 1024 + q * 512]);
  };

  stage(0, 0);
  stage(1, 64);
  asm volatile("s_waitcnt vmcnt(6)" ::: "memory");
  __builtin_amdgcn_s_barrier();
  __builtin_amdgcn_sched_barrier(0);

  int cur = 0, nxt = 2;
  for (int t = 0; t < 16; ++t) {
    const bool pf = (t + 2 < 16);
    if (pf) stage(nxt, (size_t)(t + 2) * 64);
    __builtin_amdgcn_sched_barrier(0);

    #pragma unroll
    for (int kk = 0; kk < 2; ++kk) {
      const bf16* aB = &As[cur][wm * 64 + o[kk]];
      const bf16* bB = &Bs[cur][wn * 64 + o[kk]];
      s16x8 af[4], bfr[4];
      #pragma unroll
      for (int i = 0; i < 4; ++i) af[i] = *(const s16x8*)(aB + i * 1024);
      #pragma unroll
      for (int j = 0; j < 4; ++j) bfr[j] = *(const s16x8*)(bB + j * 1024);
      __builtin_amdgcn_s_setprio(1);
      #pragma unroll
      for (int i = 0; i < 4; ++i)
        #pragma unroll
        for (int j = 0; j < 4; ++j)
          acc[i][j] = __builtin_amdgcn_mfma_f32_16x16x32_bf16(af[i], bfr[j], acc[i][j], 0, 0, 0);
      __builtin_amdgcn_s_setprio(0);
    }

    if (pf) asm volatile("s_waitcnt vmcnt(6)" ::: "memory");
    else    asm volatile("s_waitcnt vmcnt(0)" ::: "memory");
    __builtin_amdgcn_s_barrier();
    __builtin_amdgcn_sched_barrier(0);

    cur = (cur + 1 == 3) ? 0 : cur + 1;
    nxt = (nxt + 1 == 3) ? 0 : nxt + 1;
  }

  const int rq = (lane >> 4) * 4;
  const int cl = lane & 15;
  #pragma unroll
  for (int j = 0; j < 4; ++j) {
    const int gc = n0 + wn + j * 16 + cl;
    #pragma unroll
    for (int i = 0; i < 4; ++i) {
      const int gr = m0 + wm + i * 16 + rq;
      #pragma unroll
      for (int rr = 0; rr < 4; ++rr)
        C[(size_t)(gr + rr) * N + gc] = acc[i][j][rr];
    }
  }
}

// ---- chunked scan --------------------------------------------------------
__global__ __launch_bounds__(256) void scan_p1(
    const float* __restrict__ r, const bf16* __restrict__ xi)
{
  const int bid = blockIdx.x;                 // 0..1023
  const int c   = bid >> 5;                   // chunk
  const int idx = (bid & 31) * 256 + threadIdx.x;  // channel 0..8191
  const int b = idx >> 10, m = idx & 1023;
  const size_t base = ((size_t)b * 2048 + c * CS) * 1024 + m;
  float a = 1.0f, s = 0.0f;
  #pragma unroll 16
  for (int t = 0; t < CS; ++t) {
    const size_t o = base + (size_t)t * 1024;
    const float rv = r[o];
    const float xv = __bfloat162float(xi[o]);
    a *= rv;
    s = fmaf(s, rv, xv);
  }
  g_cA[c * 8192 + idx] = a;
  g_cB[c * 8192 + idx] = s;
}

__global__ __launch_bounds__(256) void scan_p2(
    const float* __restrict__ mem, float* __restrict__ memout)
{
  const int idx = blockIdx.x * 256 + threadIdx.x;  // 0..8191
  float H = mem[idx];
  #pragma unroll
  for (int c = 0; c < CH; ++c) {
    const float a = g_cA[c * 8192 + idx];
    const float s = g_cB[c * 8192 + idx];
    g_cA[c * 8192 + idx] = H;     // seed for chunk c
    H = fmaf(a, H, s);
  }
  memout[idx] = H;
}

__global__ __launch_bounds__(256) void scan_p3(
    const float* __restrict__ r, bf16* xi, const bf16* __restrict__ og)
{
  const int bid = blockIdx.x;
  const int c   = bid >> 5;
  const int idx = (bid & 31) * 256 + threadIdx.x;
  const int b = idx >> 10, m = idx & 1023;
  const size_t base = ((size_t)b * 2048 + c * CS) * 1024 + m;
  float h = g_cA[c * 8192 + idx];
  #pragma unroll 8
  for (int t = 0; t < CS; ++t) {
    const size_t o = base + (size_t)t * 1024;
    const float rv = r[o];
    const float xv = __bfloat162float(xi[o]);
    const float ov = __bfloat162float(og[o]);
    h = fmaf(h, rv, xv);
    xi[o] = __float2bfloat16(h / (1.0f + fabsf(h)) * ov);
  }
}

extern "C" void kernel_launch(void* const* d_in, const int* in_sizes, int n_in,
                              void* d_out, int out_size, void* d_ws, size_t ws_size,
                              hipStream_t stream)
{
  const float* x     = (const float*)d_in[0];
  const float* mem   = (const float*)d_in[1];
  const float* wr_w  = (const float*)d_in[2];
  const float* wr_b  = (const float*)d_in[3];
  const float* wi_w  = (const float*)d_in[4];
  const float* wig_w = (const float*)d_in[5];
  const float* wig_b = (const float*)d_in[6];
  const float* wog_w = (const float*)d_in[7];
  const float* wog_b = (const float*)d_in[8];
  const float* wo_w  = (const float*)d_in[9];
  float* out = (float*)d_out;

  const int M = 16384, N = 1024, K = 1024;
  const size_t MN = (size_t)M * N;

  // ws: [r f32: 64 MiB][xi bf16: 32 MiB]  (96 MiB; proven available)
  float* r  = (float*)d_ws;
  bf16*  xi = (bf16*)((char*)d_ws + MN * 4);

  bf16* xb = nullptr, *wb = nullptr, *og = nullptr;
  hipGetSymbolAddress((void**)&xb, HIP_SYMBOL(g_xb));
  hipGetSymbolAddress((void**)&wb, HIP_SYMBOL(g_wb));
  hipGetSymbolAddress((void**)&og, HIP_SYMBOL(g_og));

  dim3 block(256);

  // 1) convert x and 5 weights to bf16
  conv_kernel<<<dim3(2048), block, 0, stream>>>(x, xb, (int)(MN / 4));
  const int W4 = 1024 * 1024 / 4;
  conv_kernel<<<dim3(256), block, 0, stream>>>(wr_w,  wb + 0 * 1024 * 1024, W4);
  conv_kernel<<<dim3(256), block, 0, stream>>>(wi_w,  wb + 1 * 1024 * 1024, W4);
  conv_kernel<<<dim3(256), block, 0, stream>>>(wig_w, wb + 2 * 1024 * 1024, W4);
  conv_kernel<<<dim3(256), block, 0, stream>>>(wog_w, wb + 3 * 1024 * 1024, W4);
  conv_kernel<<<dim3(256), block, 0, stream>>>(wo_w,  wb + 4 * 1024 * 1024, W4);

  // 2+3) all four projections in one pass:
  //      r = sigmoid(x@wr^T+b), og = sigmoid(x@wog^T+b),
  //      xi = (x@wi^T) * sigmoid(x@wig^T+b)
  gemm_quad<<<dim3(64, 16), dim3(512), 0, stream>>>(
      xb,
      wb + 0 * 1024 * 1024,   // wr
      wb + 3 * 1024 * 1024,   // wog
      wb + 1 * 1024 * 1024,   // wi
      wb + 2 * 1024 * 1024,   // wig
      wr_b, wog_b, wig_b,
      r, og, xi, M, N, K);

  // 4) chunked scan; z in-place over xi; mem_out -> out tail (f32)
  scan_p1<<<dim3(1024), block, 0, stream>>>(r, xi);
  scan_p2<<<dim3(32),   block, 0, stream>>>(mem, out + MN);
  scan_p3<<<dim3(1024), block, 0, stream>>>(r, xi, og);

  // 5) y = z @ wo^T
  gemm_single<<<dim3(64, 8), dim3(512), 0, stream>>>(
      xi, wb + 4 * 1024 * 1024, out, M, N, K);
}